// Round 11
// baseline (91.206 us; speedup 1.0000x reference)
//
#include <hip/hip_runtime.h>

typedef __attribute__((ext_vector_type(2))) _Float16 h2;
typedef __attribute__((ext_vector_type(2))) __fp16 p2;   // cvt_pkrtz return type
typedef __attribute__((ext_vector_type(8))) _Float16 f16x8;
typedef __attribute__((ext_vector_type(4))) float fv4;
typedef __attribute__((ext_vector_type(4))) int iv4;
typedef __attribute__((ext_vector_type(2))) int iv2;

#define K_IN 4096
#define N_OUT 4096
#define KE 4160   /* 4096 data + 16 lora + 48 zero pad */
#define NG 520    /* granules (8 f16) per row */

// Fragment-major layout: f16 element (row, k) of a matrix with R rows lives at
//   base[(((row>>4)*NG + (k>>3))*16 + (row&15))*8 + (k&7)]
// so one wave MFMA-fragment load (lane = rl + 16*hq, granule g0+hq) is a
// single fully-contiguous 1KB global_load_dwordx4.

// ---------------------------------------------------------------------------
// Fused prep (one launch):
//   bid <  1024        : x row bid -> xp (+ xa dots into granules 512..519)
//   1024 <= bid < 5120 : W dequant, o-row = bid-1024, group = t
//   5120 <= bid < 5248 : W lora/zero cols (granules 512..519)
// ---------------------------------------------------------------------------
__global__ __launch_bounds__(256) void prep_all(
        const float* __restrict__ x, const float* __restrict__ la,
        const int* __restrict__ qw, const float* __restrict__ sc,
        const float* __restrict__ lb, const float* __restrict__ alphap,
        _Float16* __restrict__ xp, _Float16* __restrict__ Wp)
{
    int bid = blockIdx.x;
    int t = threadIdx.x;
    if (bid < 1024) {
        int b = bid;
        int rb = b >> 4, rl = b & 15;
        const fv4* xv4 = (const fv4*)(x + (size_t)b * K_IN);
        fv4 xv[4];
#pragma unroll
        for (int j = 0; j < 4; ++j) xv[j] = xv4[t + j * 256];
        // write main f16 data (8B per write, half-granule)
#pragma unroll
        for (int j = 0; j < 4; ++j) {
            int idx = t + j * 256;            // 0..1023, k0 = idx*4
            int g = idx >> 1, sub = (idx & 1) * 4;
            union { p2 h[2]; iv2 v; } u;
            u.h[0] = __builtin_amdgcn_cvt_pkrtz(xv[j].x, xv[j].y);
            u.h[1] = __builtin_amdgcn_cvt_pkrtz(xv[j].z, xv[j].w);
            *(iv2*)(xp + (((size_t)rb * NG + g) * 16 + rl) * 8 + sub) = u.v;
        }
        // 16 dots with lora_a rows (la 256KB -> L2-resident)
        float acc[16];
#pragma unroll
        for (int r = 0; r < 16; ++r) {
            const fv4* ap = (const fv4*)(la + (size_t)r * K_IN);
            float s = 0.f;
#pragma unroll
            for (int j = 0; j < 4; ++j) {
                fv4 av = ap[t + j * 256];
                s = fmaf(xv[j].x, av.x, s);
                s = fmaf(xv[j].y, av.y, s);
                s = fmaf(xv[j].z, av.z, s);
                s = fmaf(xv[j].w, av.w, s);
            }
            acc[r] = s;
        }
#pragma unroll
        for (int r = 0; r < 16; ++r) {
#pragma unroll
            for (int off = 1; off < 64; off <<= 1)
                acc[r] += __shfl_xor(acc[r], off);
        }
        __shared__ float red[4][16];
        int lane = t & 63, w = t >> 6;
        if (lane < 16) red[w][lane] = acc[lane];
        __syncthreads();
        if (t < 64) {
            // k = 4096 + t : granule 512 + (t>>3), elem t&7
            float v = (t < 16) ? (red[0][t] + red[1][t] + red[2][t] + red[3][t]) : 0.f;
            int g = 512 + (t >> 3), e = t & 7;
            xp[(((size_t)rb * NG + g) * 16 + rl) * 8 + e] = (_Float16)v;
        }
    } else if (bid < 5120) {
        int o = bid - 1024;                  // output col (W row) 0..4095
        int gi = t;                          // 16-weight group 0..255
        int cb = o >> 4, rl = o & 15;
        const int* qp = qw + ((size_t)o * 256 + gi) * 8;
        iv4 q0 = *(const iv4*)qp;
        iv4 q1 = *(const iv4*)(qp + 4);
        float s = sc[(size_t)o * 256 + gi];
        _Float16 c0h = (_Float16)(s * (2.0f / 15.0f));
        _Float16 c1h = (_Float16)(-s);
        h2 c0 = {c0h, c0h}, c1 = {c1h, c1h};
        h2 m1024 = {(_Float16)-1024.f, (_Float16)-1024.f};
        union { h2 h[4]; iv4 v; } o0, o1;
        int vals[8] = {q0.x, q0.y, q0.z, q0.w, q1.x, q1.y, q1.z, q1.w};
#pragma unroll
        for (int e = 0; e < 8; ++e) {
            unsigned wv = (unsigned)vals[e];
            unsigned qb = (wv & 15u) | ((wv & 0xF0u) << 12) | 0x64006400u;
            h2 qh;
            __builtin_memcpy(&qh, &qb, 4);
            h2 r = (qh + m1024) * c0 + c1;
            if (e < 4) o0.h[e] = r; else o1.h[e - 4] = r;
        }
        // group gi = granules 2gi (elems 0..7) and 2gi+1 (elems 8..15)
        _Float16* w0 = Wp + (((size_t)cb * NG + 2 * gi) * 16 + rl) * 8;
        *(iv4*)(w0) = o0.v;
        *(iv4*)(w0 + 128) = o1.v;            // next granule = +16*8 f16
    } else {
        int c = (bid - 5120) * 256 + t;      // 0..32767 : o = c>>3, g 512+(c&7)
        int o = c >> 3, jj = c & 7;
        int cb = o >> 4, rl = o & 15;
        union { p2 h[4]; iv4 v; } u;
        u.v = iv4{0, 0, 0, 0};
        if (jj < 2) {
            float al = alphap[0];
            const float* wp = lb + (size_t)o * 16 + jj * 8;
#pragma unroll
            for (int e = 0; e < 4; ++e)
                u.h[e] = __builtin_amdgcn_cvt_pkrtz(al * wp[2 * e], al * wp[2 * e + 1]);
        }
        *(iv4*)(Wp + (((size_t)cb * NG + 512 + jj) * 16 + rl) * 8) = u.v;
    }
}

// ---------------------------------------------------------------------------
// GEMM: out = X[1024][KE] @ W[4096][KE]^T, f32 accum, fragment-major inputs.
// 256 blocks x 512 thr (8 waves: wm,wn,kg = 2x2x2; wave 64x64 over its k32
// half of each BK=64 step; 65 steps). NO LDS / NO barriers in the main loop:
// each fragment is one contiguous 1KB global_load_dwordx4 from L2; dist-1
// register double-buffer (named sets), compiler emits counted vmcnt.
// LDS (64KB) used only for the kg-split epilogue reduction.
// XCD map: each XCD owns 8by x 4bx -> its B strip L2-resident.
// ---------------------------------------------------------------------------
__global__ __launch_bounds__(512, 1) void qlora_gemm2(
        const _Float16* __restrict__ xp, const _Float16* __restrict__ Wp,
        float* __restrict__ out)
{
    __shared__ __align__(16) char lds[65536];

    int bid = blockIdx.x;
    int xcd = bid & 7, j = bid >> 3;    // j 0..31
    int by = j & 7, bx = xcd * 4 + (j >> 3);
    int bm0 = by << 7, bn0 = bx << 7;

    int t = threadIdx.x;
    int lane = t & 63;
    int wid = t >> 6;                   // 0..7
    int kg = wid & 1, wn = (wid >> 1) & 1, wm = wid >> 2;
    int rl = lane & 15, hq = lane >> 4;

    // per-lane fragment base addresses (granule g = ts*8 + kg*4 + hq)
    const char* abase[4];
    const char* bbase[4];
#pragma unroll
    for (int m = 0; m < 4; ++m) {
        int rb = by * 8 + wm * 4 + m;
        abase[m] = (const char*)xp + (((size_t)rb * NG + kg * 4 + hq) * 16 + rl) * 16;
    }
#pragma unroll
    for (int n = 0; n < 4; ++n) {
        int cb = bx * 8 + wn * 4 + n;
        bbase[n] = (const char*)Wp + (((size_t)cb * NG + kg * 4 + hq) * 16 + rl) * 16;
    }

    struct Frag { iv4 a[4]; iv4 b[4]; };
    Frag fA, fB;

    auto LOADF = [&](Frag& f, int ts) {
        size_t off = (size_t)ts * 2048;   // 8 granules * 256B
#pragma unroll
        for (int m = 0; m < 4; ++m) f.a[m] = *(const iv4*)(abase[m] + off);
#pragma unroll
        for (int n = 0; n < 4; ++n) f.b[n] = *(const iv4*)(bbase[n] + off);
    };

    fv4 acc[4][4];
#pragma unroll
    for (int m = 0; m < 4; ++m)
#pragma unroll
        for (int n = 0; n < 4; ++n)
            acc[m][n] = fv4{0.f, 0.f, 0.f, 0.f};

    auto MFMAF = [&](const Frag& f) {
        union { iv4 v; f16x8 h; } ua[4], ub[4];
#pragma unroll
        for (int m = 0; m < 4; ++m) ua[m].v = f.a[m];
#pragma unroll
        for (int n = 0; n < 4; ++n) ub[n].v = f.b[n];
        __builtin_amdgcn_s_setprio(1);
#pragma unroll
        for (int m = 0; m < 4; ++m)
#pragma unroll
            for (int n = 0; n < 4; ++n)
                acc[m][n] = __builtin_amdgcn_mfma_f32_16x16x32_f16(
                    ua[m].h, ub[n].h, acc[m][n], 0, 0, 0);
        __builtin_amdgcn_s_setprio(0);
    };

    // ---- main loop: 65 steps, register double-buffer, no barriers ----
    LOADF(fA, 0);
#pragma unroll 1
    for (int ts = 0; ts < 64; ts += 2) {
        LOADF(fB, ts + 1);
        MFMAF(fA);
        LOADF(fA, ts + 2);
        MFMAF(fB);
    }
    MFMAF(fA);                           // ts = 64

    // ---- kg-split reduction + store (LDS only here) ----
    __syncthreads();
    if (kg == 1) {
        char* dmp = lds + (wm * 2 + wn) * 16384;
#pragma unroll
        for (int m = 0; m < 4; ++m)
#pragma unroll
            for (int n = 0; n < 4; ++n)
                *(fv4*)(dmp + (m * 4 + n) * 1024 + lane * 16) = acc[m][n];
    }
    __syncthreads();
    if (kg == 0) {
        const char* dmp = lds + (wm * 2 + wn) * 16384;
#pragma unroll
        for (int m = 0; m < 4; ++m) {
            int row0 = bm0 + wm * 64 + m * 16 + hq * 4;
#pragma unroll
            for (int n = 0; n < 4; ++n) {
                fv4 p = *(const fv4*)(dmp + (m * 4 + n) * 1024 + lane * 16);
                fv4 v = acc[m][n];
                v.x += p.x; v.y += p.y; v.z += p.z; v.w += p.w;
                int col = bn0 + wn * 64 + n * 16 + rl;
#pragma unroll
                for (int r = 0; r < 4; ++r)
                    out[(size_t)(row0 + r) * N_OUT + col] = v[r];
            }
        }
    }
}

extern "C" void kernel_launch(void* const* d_in, const int* in_sizes, int n_in,
                              void* d_out, int out_size, void* d_ws, size_t ws_size,
                              hipStream_t stream) {
    const float* x  = (const float*)d_in[0];
    const int*   qw = (const int*)d_in[1];
    const float* sc = (const float*)d_in[2];
    const float* la = (const float*)d_in[3];
    const float* lb = (const float*)d_in[4];
    const float* al = (const float*)d_in[5];
    float* out = (float*)d_out;

    const size_t WP_BYTES = (size_t)(N_OUT / 16) * NG * 16 * 16;  // 34,078,720
    _Float16* Wp = (_Float16*)d_ws;
    _Float16* xp = (_Float16*)((char*)d_ws + WP_BYTES);
    (void)ws_size; (void)n_in; (void)in_sizes; (void)out_size;

    prep_all<<<5248, 256, 0, stream>>>(x, la, qw, sc, lb, al, xp, Wp);
    qlora_gemm2<<<256, 512, 0, stream>>>(xp, Wp, out);
}